// Round 5
// baseline (269.761 us; speedup 1.0000x reference)
//
#include <hip/hip_runtime.h>
#include <hip/hip_bf16.h>

typedef __bf16 bf16x8 __attribute__((ext_vector_type(8)));
typedef float floatx4 __attribute__((ext_vector_type(4)));
typedef unsigned short u16;

constexpr int T_DIM = 2048;
constexpr int H_DIM = 4096;
constexpr int O_DIM = 4096;
constexpr int R_DIM = 16;
constexpr int L_DIM = 32;
constexpr int GSZ = 8;  // tokens per epilogue block

constexpr int NX4 = T_DIM * H_DIM / 4;
constexpr int NW4 = O_DIM * H_DIM / 4;
constexpr int NA4 = L_DIM * R_DIM * H_DIM / 4;
constexpr int NTOT4 = NX4 + NW4 + NA4;            // float4 count (region bounds 1024-aligned)
constexpr int NCVT_BLK = 2048;                    // grid-stride convert blocks
constexpr int NZ4 = (T_DIM * R_DIM / 4) / 1024;   // 8 zero blocks

// ---------------- fp32 -> bf16 (RNE) ----------------
__device__ __forceinline__ u16 f2bf_rne(float f) {
  unsigned int u = __float_as_uint(f);
  u += 0x7fffu + ((u >> 16) & 1u);
  return (u16)(u >> 16);
}

// ---------------- pre: convert x/w/lora_a -> bf16 (grid-stride), bucket, zero shrunk ----------------
__global__ __launch_bounds__(256) void pre_kernel(const float4* __restrict__ x,
                                                  const float4* __restrict__ w,
                                                  const float4* __restrict__ a,
                                                  ushort4* __restrict__ xb,
                                                  ushort4* __restrict__ wb,
                                                  ushort4* __restrict__ ab,
                                                  const int* __restrict__ idx,
                                                  int* __restrict__ offs,
                                                  int* __restrict__ list,
                                                  float* __restrict__ shrunk) {
  const int bid = blockIdx.x;
  const int tid = threadIdx.x;
  if (bid < NCVT_BLK) {
    for (int base = bid * 1024; base < NTOT4; base += NCVT_BLK * 1024) {
      float4 v[4];
      ushort4* d[4];
#pragma unroll
      for (int c = 0; c < 4; ++c) {
        int i = base + c * 256 + tid;
        if (i < NX4) { v[c] = x[i]; d[c] = xb + i; }
        else if (i < NX4 + NW4) { v[c] = w[i - NX4]; d[c] = wb + (i - NX4); }
        else { v[c] = a[i - NX4 - NW4]; d[c] = ab + (i - NX4 - NW4); }
      }
#pragma unroll
      for (int c = 0; c < 4; ++c) {
        ushort4 r;
        r.x = f2bf_rne(v[c].x); r.y = f2bf_rne(v[c].y);
        r.z = f2bf_rne(v[c].z); r.w = f2bf_rne(v[c].w);
        *d[c] = r;
      }
    }
    return;
  }
  if (bid > NCVT_BLK) {
    // zero shrunk
    float4 z = {0.f, 0.f, 0.f, 0.f};
#pragma unroll
    for (int c = 0; c < 4; ++c) {
      int i = (bid - NCVT_BLK - 1) * 1024 + c * 256 + tid;
      ((float4*)shrunk)[i] = z;
    }
    return;
  }
  // bucket block: sort tokens by l (inactives last)
  __shared__ int cnt[L_DIM + 1];
  __shared__ int base_[L_DIM + 1];
  __shared__ int cur[L_DIM + 1];
  if (tid <= L_DIM) cnt[tid] = 0;
  __syncthreads();
  for (int t = tid; t < T_DIM; t += 256) {
    int l = idx[t];
    atomicAdd(&cnt[l >= 0 ? l : L_DIM], 1);
  }
  __syncthreads();
  if (tid == 0) {
    int acc = 0;
    for (int l = 0; l <= L_DIM; ++l) { base_[l] = acc; acc += cnt[l]; }
  }
  __syncthreads();
  if (tid <= L_DIM) {
    cur[tid] = 0;
    offs[tid] = base_[tid];  // offs[32] = #active tokens
  }
  __syncthreads();
  for (int t = tid; t < T_DIM; t += 256) {
    int l = idx[t];
    int b = l >= 0 ? l : L_DIM;
    int p = base_[b] + atomicAdd(&cur[b], 1);
    list[p] = t;
  }
}

// ---------------- async 16B global->LDS ----------------
__device__ __forceinline__ void async16(const u16* g, char* l) {
  __builtin_amdgcn_global_load_lds((const __attribute__((address_space(1))) unsigned int*)g,
                                   (__attribute__((address_space(3))) unsigned int*)l,
                                   16, 0, 0);
}

// ---------------- fused GEMM (128x128, split-K=2, 2 blocks/CU) + shrink ----------------
// Occupancy experiment: dbuf LDS = 64 KiB -> 2 independent blocks per CU; one
// block's MFMA clusters cover the other's barrier/vmcnt stalls (cross-block
// overlap, m114). 256 thr = 2x2 waves, wave-tile 64x64. Tile body is the
// R4-proven 2-phase pattern: {ds_read; (stage); barrier; lgkmcnt(0); setprio(1);
// 16 MFMA; setprio(0); barrier} x2, ONE vmcnt(0) per tile boundary. Chunk-XOR
// both-sides swizzle (bank-conflict 0 proven). Shrink rides along as the first
// 128 blocks (depends only on pre; epilogue needs it -> same launch is legal).
constexpr int NSHR = 128;             // shrink blocks
constexpr int BK = 64;
constexpr int NT = (H_DIM / 2) / BK;  // 32 K-tiles per split-K half
// LDS: A0 @0 (16K) | A1 @16K | B0 @32K | B1 @48K  (128 rows x 128B each)

__device__ __forceinline__ void stage8(const u16* gA, const u16* gB,
                                       char* dA, char* dB, int kk) {
#pragma unroll
  for (int c = 0; c < 4; ++c) async16(gA + c * (32 * H_DIM) + kk, dA + c * 4096);
#pragma unroll
  for (int c = 0; c < 4; ++c) async16(gB + c * (32 * H_DIM) + kk, dB + c * 4096);
}

__device__ __forceinline__ void tile2(floatx4 (&acc)[4][4],
                                      const char* a, const char* b,
                                      int x0, int x1,
                                      const u16* gA, const u16* gB,
                                      char* dA, char* dB,
                                      bool dostage, int kk) {
  bf16x8 af[4][2], b01[2][2], b23[2][2];

  // ---- P1: read A i0-3 (8) + B n0-1 (4); stage next tile (8); MFMA 16 ----
#pragma unroll
  for (int i = 0; i < 4; ++i) {
    af[i][0] = *(const bf16x8*)(a + x0 + i * 2048);
    af[i][1] = *(const bf16x8*)(a + x1 + i * 2048);
  }
#pragma unroll
  for (int n = 0; n < 2; ++n) {
    b01[n][0] = *(const bf16x8*)(b + x0 + n * 2048);
    b01[n][1] = *(const bf16x8*)(b + x1 + n * 2048);
  }
  if (dostage) stage8(gA, gB, dA, dB, kk);
  __builtin_amdgcn_s_barrier();
  asm volatile("s_waitcnt lgkmcnt(0)" ::: "memory");
  __builtin_amdgcn_s_setprio(1);
#pragma unroll
  for (int i = 0; i < 4; ++i)
#pragma unroll
    for (int n = 0; n < 2; ++n) {
      acc[i][n] = __builtin_amdgcn_mfma_f32_16x16x32_bf16(af[i][0], b01[n][0], acc[i][n], 0, 0, 0);
      acc[i][n] = __builtin_amdgcn_mfma_f32_16x16x32_bf16(af[i][1], b01[n][1], acc[i][n], 0, 0, 0);
    }
  __builtin_amdgcn_s_setprio(0);
  __builtin_amdgcn_s_barrier();

  // ---- P2: read B n2-3 (4); MFMA 16 (reuse af); tile-boundary drain ----
#pragma unroll
  for (int n = 0; n < 2; ++n) {
    b23[n][0] = *(const bf16x8*)(b + x0 + (n + 2) * 2048);
    b23[n][1] = *(const bf16x8*)(b + x1 + (n + 2) * 2048);
  }
  __builtin_amdgcn_s_barrier();
  asm volatile("s_waitcnt lgkmcnt(0)" ::: "memory");
  __builtin_amdgcn_s_setprio(1);
#pragma unroll
  for (int i = 0; i < 4; ++i)
#pragma unroll
    for (int n = 0; n < 2; ++n) {
      acc[i][n + 2] = __builtin_amdgcn_mfma_f32_16x16x32_bf16(af[i][0], b23[n][0], acc[i][n + 2], 0, 0, 0);
      acc[i][n + 2] = __builtin_amdgcn_mfma_f32_16x16x32_bf16(af[i][1], b23[n][1], acc[i][n + 2], 0, 0, 0);
    }
  __builtin_amdgcn_s_setprio(0);
  asm volatile("s_waitcnt vmcnt(0)" ::: "memory");
  __builtin_amdgcn_s_barrier();
}

__global__ __launch_bounds__(256, 2) void gemm_shrink_kernel(const u16* __restrict__ Abf,
                                                             const u16* __restrict__ Bbf,
                                                             float* __restrict__ dest0,
                                                             float* __restrict__ dest1,
                                                             const float* __restrict__ bias,
                                                             const u16* __restrict__ ab,
                                                             const int* __restrict__ offs,
                                                             const int* __restrict__ list,
                                                             float* __restrict__ shrunk) {
  __shared__ __align__(16) char lds[65536];
  const int tid = threadIdx.x;

  if (blockIdx.x < NSHR) {
    // ---------------- shrink path (unchanged logic; l = bid&31, kq = bid>>5) ----------------
    const int l = blockIdx.x & 31;
    const int kbase = (blockIdx.x >> 5) * (H_DIM / 4);
    const int off = offs[l];
    const int n = offs[l + 1] - off;
    if (n == 0) return;
    const int wave = tid >> 6, lane = tid & 63;
    const int quad = lane >> 4, mn = lane & 15;
    const int ngroups = (n + 15) / 16;
    const u16* arow = ab + ((long)l * R_DIM + mn) * H_DIM + quad * 8 + kbase;  // r = mn

    for (int g = wave; g < ngroups; g += 4) {
      int p = off + g * 16 + mn;
      int pc = off + n - 1;
      int tok = list[p < pc ? p : pc];  // clamp for partial groups
      const u16* xrow = Abf + (long)tok * H_DIM + quad * 8 + kbase;
      floatx4 acc = {0.f, 0.f, 0.f, 0.f};
#pragma unroll 8
      for (int k = 0; k < H_DIM / 4; k += 32) {
        bf16x8 xf = *(const bf16x8*)(xrow + k);
        bf16x8 af = *(const bf16x8*)(arow + k);
        acc = __builtin_amdgcn_mfma_f32_16x16x32_bf16(xf, af, acc, 0, 0, 0);
      }
#pragma unroll
      for (int r = 0; r < 4; ++r) {
        int trow = g * 16 + quad * 4 + r;
        if (trow < n) atomicAdd(&shrunk[list[off + trow] * R_DIM + mn], acc[r]);
      }
    }
    return;
  }

  // ---------------- gemm path ----------------
  const int lane = tid & 63;
  const int wave = tid >> 6;
  const int wr = wave >> 1;   // 0..1  M half (64 rows)
  const int wc = wave & 1;    // 0..1  N half (64 cols)
  const int quad = lane >> 4, mn = lane & 15;

  // T1: bijective XCD swizzle over 1024 gemm blocks (128 consecutive per XCD)
  const int flat = blockIdx.x - NSHR;
  const int swz = (flat & 7) * 128 + (flat >> 3);
  const int tx = swz & 31;          // o tile (0..31)
  const int ty = (swz >> 5) & 15;   // t tile (0..15)
  const int tz = swz >> 9;          // split-K half
  const int t0 = ty * 128;
  const int o0 = tx * 128;
  const int kbase = tz * (H_DIM / 2);
  float* const dest = tz ? dest1 : dest0;

  // staging: chunk m = c*256+tid -> phys (row=m>>3 = c*32 + tid>>3, slot=tid&7);
  // slot holds logical cc = slot^(row&7); row&7 = (tid>>3)&7, c-invariant.
  const int srow = tid >> 3;
  const int cc = (tid & 7) ^ (srow & 7);
  const u16* const gA = Abf + (long)(t0 + srow) * H_DIM + kbase + cc * 8;
  const u16* const gB = Bbf + (long)(o0 + srow) * H_DIM + kbase + cc * 8;
  char* const dA = lds + tid * 16;
  char* const dB = lds + 32768 + tid * 16;

  // ds_read: logical (row, chunk k) at byte row*128 + (k ^ (row&7))*16
  const int x0 = (quad ^ (mn & 7)) * 16;           // K-slice 0
  const int x1 = ((quad + 4) ^ (mn & 7)) * 16;     // K-slice 1
  const char* const pA = lds + (wr * 64 + mn) * 128;
  const char* const pB = lds + 32768 + (wc * 64 + mn) * 128;

  floatx4 acc[4][4] = {};

  // prologue: tile 0 -> buf0 (8 loads), wait, barrier
  stage8(gA, gB, dA, dB, 0);
  asm volatile("s_waitcnt vmcnt(0)" ::: "memory");
  __builtin_amdgcn_s_barrier();

#pragma unroll 1
  for (int kt = 0; kt < NT; kt += 2) {
    // tile kt from buf0, stage kt+1 -> buf1
    tile2(acc, pA, pB, x0, x1, gA, gB, dA + 16384, dB + 16384, true, (kt + 1) * BK);
    // tile kt+1 from buf1, stage kt+2 -> buf0
    tile2(acc, pA + 16384, pB + 16384, x0, x1, gA, gB, dA, dB,
          kt + 2 < NT, (kt + 2) * BK);
  }

  // C/D layout: row = quad*4 + reg (A-tile i), col = mn (B-tile n).
  // z=0 half fuses bias; z=1 writes raw partial.
  float bv[4];
#pragma unroll
  for (int n = 0; n < 4; ++n) bv[n] = tz ? 0.f : bias[o0 + wc * 64 + n * 16 + mn];
#pragma unroll
  for (int i = 0; i < 4; ++i) {
#pragma unroll
    for (int r = 0; r < 4; ++r) {
      float* orow = dest + (long)(t0 + wr * 64 + i * 16 + quad * 4 + r) * O_DIM
                    + o0 + wc * 64 + mn;
#pragma unroll
      for (int n = 0; n < 4; ++n) orow[n * 16] = acc[i][n][r] + bv[n];
    }
  }
}

// ---------------- epilogue: out += part1 (+ lora delta for active tokens) ----------------
// token-grouped over sorted list (B reuse), block-uniform B reload branch.
__global__ __launch_bounds__(256) void epilogue_kernel(float* __restrict__ out,
                                                       const float* __restrict__ part1,
                                                       const float* __restrict__ shrunk,
                                                       const float* __restrict__ lora_b,
                                                       const int* __restrict__ idx,
                                                       const int* __restrict__ list) {
  const int o = blockIdx.x * 1024 + threadIdx.x * 4;
  const int g0 = blockIdx.y * GSZ;

  int ts[GSZ], ls[GSZ];
#pragma unroll
  for (int gi = 0; gi < GSZ; ++gi) ts[gi] = list[g0 + gi];
#pragma unroll
  for (int gi = 0; gi < GSZ; ++gi) {
    int l = idx[ts[gi]];
    ls[gi] = l < 0 ? 0 : l;  // shrunk row is zero when l<0 -> dot = 0
  }

  float4 B[4][4];
  int lcur = -1;
#pragma unroll
  for (int gi = 0; gi < GSZ; ++gi) {
    const int t = ts[gi];
    if (ls[gi] != lcur) {  // block-uniform branch
      lcur = ls[gi];
      const float4* bg = (const float4*)(lora_b + ((long)lcur * O_DIM + o) * R_DIM);
#pragma unroll
      for (int j = 0; j < 4; ++j)
#pragma unroll
        for (int q = 0; q < 4; ++q) B[j][q] = bg[j * 4 + q];
    }
    const float4* sp = (const float4*)(shrunk + t * R_DIM);
    float4 s0 = sp[0], s1 = sp[1], s2 = sp[2], s3 = sp[3];
    float4 v = *(const float4*)(out + (long)t * O_DIM + o);
    float4 p = *(const float4*)(part1 + (long)t * O_DIM + o);
    v.x += p.x; v.y += p.y; v.z += p.z; v.w += p.w;
    float* vp = &v.x;
#pragma unroll
    for (int j = 0; j < 4; ++j) {
      float d = s0.x * B[j][0].x + s0.y * B[j][0].y + s0.z * B[j][0].z + s0.w * B[j][0].w;
      d += s1.x * B[j][1].x + s1.y * B[j][1].y + s1.z * B[j][1].z + s1.w * B[j][1].w;
      d += s2.x * B[j][2].x + s2.y * B[j][2].y + s2.z * B[j][2].z + s2.w * B[j][2].w;
      d += s3.x * B[j][3].x + s3.y * B[j][3].y + s3.z * B[j][3].z + s3.w * B[j][3].w;
      vp[j] += d;
    }
    *(float4*)(out + (long)t * O_DIM + o) = v;
  }
}

extern "C" void kernel_launch(void* const* d_in, const int* in_sizes, int n_in,
                              void* d_out, int out_size, void* d_ws, size_t ws_size,
                              hipStream_t stream) {
  (void)in_sizes; (void)n_in; (void)out_size; (void)ws_size;
  const float* x      = (const float*)d_in[0];
  const float* w      = (const float*)d_in[1];
  const float* bias   = (const float*)d_in[2];
  const float* lora_a = (const float*)d_in[3];
  const float* lora_b = (const float*)d_in[4];
  const int*   idx    = (const int*)d_in[5];
  float* out = (float*)d_out;

  char* ws = (char*)d_ws;
  const size_t OFF_XB = 0;                               // 16 MiB  x bf16
  const size_t OFF_WB = (size_t)16 << 20;                // 32 MiB  w bf16
  const size_t OFF_SHRUNK = (size_t)48 << 20;            // 128 KiB
  const size_t OFF_LIST = OFF_SHRUNK + 131072;           // 8 KiB
  const size_t OFF_OFFS = OFF_LIST + 8192;               // 136 B
  const size_t OFF_PART = (size_t)49 << 20;              // 32 MiB fp32 partial1
  const size_t OFF_AB = (size_t)81 << 20;                // 4 MiB lora_a bf16 (no overlay:
  // shrink now runs concurrently with gemm, which clobbers part1)

  u16* xb = (u16*)(ws + OFF_XB);
  u16* wb = (u16*)(ws + OFF_WB);
  u16* ab = (u16*)(ws + OFF_AB);
  float* shrunk = (float*)(ws + OFF_SHRUNK);
  int* list = (int*)(ws + OFF_LIST);
  int* offs = (int*)(ws + OFF_OFFS);
  float* part1 = (float*)(ws + OFF_PART);

  pre_kernel<<<NCVT_BLK + 1 + NZ4, 256, 0, stream>>>(
      (const float4*)x, (const float4*)w, (const float4*)lora_a,
      (ushort4*)xb, (ushort4*)wb, (ushort4*)ab, idx, offs, list, shrunk);

  // shrink (128 blocks) + gemm (1024 blocks) fused in one launch
  gemm_shrink_kernel<<<NSHR + 1024, 256, 0, stream>>>(
      xb, wb, out, part1, bias, ab, offs, list, shrunk);

  dim3 egrid(O_DIM / 1024, T_DIM / GSZ);
  epilogue_kernel<<<egrid, 256, 0, stream>>>(out, part1, shrunk, lora_b, idx, list);
}

// Round 6
// 250.486 us; speedup vs baseline: 1.0769x; 1.0769x over previous
//
#include <hip/hip_runtime.h>
#include <hip/hip_bf16.h>

typedef __bf16 bf16x8 __attribute__((ext_vector_type(8)));
typedef float floatx4 __attribute__((ext_vector_type(4)));
typedef unsigned short u16;

constexpr int T_DIM = 2048;
constexpr int H_DIM = 4096;
constexpr int O_DIM = 4096;
constexpr int R_DIM = 16;
constexpr int L_DIM = 32;

constexpr int NX4 = T_DIM * H_DIM / 4;
constexpr int NW4 = O_DIM * H_DIM / 4;
constexpr int NA4 = L_DIM * R_DIM * H_DIM / 4;
constexpr int NTOT4 = NX4 + NW4 + NA4;            // float4 count (region bounds 1024-aligned)
constexpr int NCVT_BLK = 2048;                    // grid-stride convert blocks
constexpr int NZ4 = (T_DIM * R_DIM / 4) / 1024;   // 8 zero blocks

// ---------------- fp32 -> bf16 (RNE) ----------------
__device__ __forceinline__ u16 f2bf_rne(float f) {
  unsigned int u = __float_as_uint(f);
  u += 0x7fffu + ((u >> 16) & 1u);
  return (u16)(u >> 16);
}

// ---------------- pre: convert x/w/lora_a -> bf16 (grid-stride), bucket, zero shrunk ----------------
__global__ __launch_bounds__(256) void pre_kernel(const float4* __restrict__ x,
                                                  const float4* __restrict__ w,
                                                  const float4* __restrict__ a,
                                                  ushort4* __restrict__ xb,
                                                  ushort4* __restrict__ wb,
                                                  ushort4* __restrict__ ab,
                                                  const int* __restrict__ idx,
                                                  int* __restrict__ offs,
                                                  int* __restrict__ list,
                                                  float* __restrict__ shrunk) {
  const int bid = blockIdx.x;
  const int tid = threadIdx.x;
  if (bid < NCVT_BLK) {
    for (int base = bid * 1024; base < NTOT4; base += NCVT_BLK * 1024) {
      float4 v[4];
      ushort4* d[4];
#pragma unroll
      for (int c = 0; c < 4; ++c) {
        int i = base + c * 256 + tid;
        if (i < NX4) { v[c] = x[i]; d[c] = xb + i; }
        else if (i < NX4 + NW4) { v[c] = w[i - NX4]; d[c] = wb + (i - NX4); }
        else { v[c] = a[i - NX4 - NW4]; d[c] = ab + (i - NX4 - NW4); }
      }
#pragma unroll
      for (int c = 0; c < 4; ++c) {
        ushort4 r;
        r.x = f2bf_rne(v[c].x); r.y = f2bf_rne(v[c].y);
        r.z = f2bf_rne(v[c].z); r.w = f2bf_rne(v[c].w);
        *d[c] = r;
      }
    }
    return;
  }
  if (bid > NCVT_BLK) {
    // zero shrunk
    float4 z = {0.f, 0.f, 0.f, 0.f};
#pragma unroll
    for (int c = 0; c < 4; ++c) {
      int i = (bid - NCVT_BLK - 1) * 1024 + c * 256 + tid;
      ((float4*)shrunk)[i] = z;
    }
    return;
  }
  // bucket block: sort tokens by l (inactives last)
  __shared__ int cnt[L_DIM + 1];
  __shared__ int base_[L_DIM + 1];
  __shared__ int cur[L_DIM + 1];
  if (tid <= L_DIM) cnt[tid] = 0;
  __syncthreads();
  for (int t = tid; t < T_DIM; t += 256) {
    int l = idx[t];
    atomicAdd(&cnt[l >= 0 ? l : L_DIM], 1);
  }
  __syncthreads();
  if (tid == 0) {
    int acc = 0;
    for (int l = 0; l <= L_DIM; ++l) { base_[l] = acc; acc += cnt[l]; }
  }
  __syncthreads();
  if (tid <= L_DIM) {
    cur[tid] = 0;
    offs[tid] = base_[tid];  // offs[32] = #active tokens
  }
  __syncthreads();
  for (int t = tid; t < T_DIM; t += 256) {
    int l = idx[t];
    int b = l >= 0 ? l : L_DIM;
    int p = base_[b] + atomicAdd(&cur[b], 1);
    list[p] = t;
  }
}

// ---------------- MFMA shrink, split-K: shrunk[tok, r] += x[tok, kq] . A[l, r, kq] ----------------
__global__ __launch_bounds__(256) void lora_shrink_mfma(const u16* __restrict__ xb,
                                                        const u16* __restrict__ ab,
                                                        const int* __restrict__ offs,
                                                        const int* __restrict__ list,
                                                        float* __restrict__ shrunk) {
  const int l = blockIdx.x;
  const int kbase = blockIdx.y * (H_DIM / 4);
  const int off = offs[l];
  const int n = offs[l + 1] - off;
  if (n == 0) return;
  const int wave = threadIdx.x >> 6, lane = threadIdx.x & 63;
  const int quad = lane >> 4, mn = lane & 15;
  const int ngroups = (n + 15) / 16;
  const u16* arow = ab + ((long)l * R_DIM + mn) * H_DIM + quad * 8 + kbase;  // r = mn

  for (int g = wave; g < ngroups; g += 4) {
    int p = off + g * 16 + mn;
    int pc = off + n - 1;
    int tok = list[p < pc ? p : pc];  // clamp for partial groups
    const u16* xrow = xb + (long)tok * H_DIM + quad * 8 + kbase;
    floatx4 acc = {0.f, 0.f, 0.f, 0.f};
#pragma unroll 8
    for (int k = 0; k < H_DIM / 4; k += 32) {
      bf16x8 xf = *(const bf16x8*)(xrow + k);
      bf16x8 af = *(const bf16x8*)(arow + k);
      acc = __builtin_amdgcn_mfma_f32_16x16x32_bf16(xf, af, acc, 0, 0, 0);
    }
#pragma unroll
    for (int r = 0; r < 4; ++r) {
      int trow = g * 16 + quad * 4 + r;
      if (trow < n) atomicAdd(&shrunk[list[off + trow] * R_DIM + mn], acc[r]);
    }
  }
}

// ---------------- async 16B global->LDS ----------------
__device__ __forceinline__ void async16(const u16* g, char* l) {
  __builtin_amdgcn_global_load_lds((const __attribute__((address_space(1))) unsigned int*)g,
                                   (__attribute__((address_space(3))) unsigned int*)l,
                                   16, 0, 0);
}

__device__ __forceinline__ bf16x8 cvt8(float4 a, float4 b) {
  bf16x8 r;
  r[0] = (__bf16)a.x; r[1] = (__bf16)a.y; r[2] = (__bf16)a.z; r[3] = (__bf16)a.w;
  r[4] = (__bf16)b.x; r[5] = (__bf16)b.y; r[6] = (__bf16)b.z; r[7] = (__bf16)b.w;
  return r;
}

// ---------------- bf16 MFMA GEMM, 128x256 tile, full K, SORTED-GATHERED tokens,
// fused LoRA (second MFMA over l-range) + bias. No split-K, no part1, no epilogue.
// Main loop is the R2-verified 80 us structure verbatim (2-phase, vmcnt(6),
// chunk-XOR both-sides swizzle, XCD-bijective block swizzle). A-rows gathered
// via per-lane global_load_lds source (row base from sorted list).
constexpr int BK = 64;
constexpr int NT = H_DIM / BK;  // 64 K-tiles
// LDS: A0 @0 (16K) | A1 @16K | B0 @32K (32K) | B1 @64K. Rows 64 bf16 = 128B as
// 16B chunks; logical chunk cc at slot cc^(row&7). 6 loads/thread/tile.

__device__ __forceinline__ void stage_tile(const u16* gA0, const u16* gA1, const u16* gB,
                                           char* dstA, char* dstB, int nx, int kk) {
  async16(gA0 + kk, dstA + nx * 16384);
  async16(gA1 + kk, dstA + nx * 16384 + 8192);
#pragma unroll
  for (int q = 0; q < 4; ++q)
    async16(gB + q * (64 * H_DIM) + kk, dstB + nx * 32768 + q * 8192);
}

__device__ __forceinline__ void ktile_body(floatx4 (&acc)[4][4],
                                           const char* pA, const char* pB,
                                           int x0, int x1, int aoff, int boff,
                                           const u16* gA0, const u16* gA1, const u16* gB,
                                           char* dstA, char* dstB,
                                           bool dostage, int nx, int kk) {
  if (dostage) {
    stage_tile(gA0, gA1, gB, dstA, dstB, nx, kk);
    asm volatile("s_waitcnt vmcnt(6)" ::: "memory");
  } else {
    asm volatile("s_waitcnt vmcnt(0)" ::: "memory");
  }
  __builtin_amdgcn_s_barrier();  // this tile's loads landed for all waves

  const char* a = pA + aoff;
  const char* b = pB + boff;
  bf16x8 af[4][2], bfr[2][2];

  // ---- P1: read A i0-3 (8) + B n0-1 (4); MFMA (M0-3 x N0-1), 16 ----
#pragma unroll
  for (int i = 0; i < 4; ++i) {
    af[i][0] = *(const bf16x8*)(a + x0 + i * 2048);
    af[i][1] = *(const bf16x8*)(a + x1 + i * 2048);
  }
#pragma unroll
  for (int n = 0; n < 2; ++n) {
    bfr[n][0] = *(const bf16x8*)(b + x0 + n * 2048);
    bfr[n][1] = *(const bf16x8*)(b + x1 + n * 2048);
  }
  __builtin_amdgcn_s_barrier();
  asm volatile("s_waitcnt lgkmcnt(0)" ::: "memory");
  __builtin_amdgcn_s_setprio(1);
#pragma unroll
  for (int i = 0; i < 4; ++i)
#pragma unroll
    for (int n = 0; n < 2; ++n) {
      acc[i][n] = __builtin_amdgcn_mfma_f32_16x16x32_bf16(af[i][0], bfr[n][0], acc[i][n], 0, 0, 0);
      acc[i][n] = __builtin_amdgcn_mfma_f32_16x16x32_bf16(af[i][1], bfr[n][1], acc[i][n], 0, 0, 0);
    }
  __builtin_amdgcn_s_setprio(0);
  __builtin_amdgcn_s_barrier();

  // ---- P2: read B n2-3 (4); MFMA (M0-3 x N2-3), 16, reuse af ----
#pragma unroll
  for (int n = 0; n < 2; ++n) {
    bfr[n][0] = *(const bf16x8*)(b + x0 + (n + 2) * 2048);
    bfr[n][1] = *(const bf16x8*)(b + x1 + (n + 2) * 2048);
  }
  __builtin_amdgcn_s_barrier();
  asm volatile("s_waitcnt lgkmcnt(0)" ::: "memory");
  __builtin_amdgcn_s_setprio(1);
#pragma unroll
  for (int i = 0; i < 4; ++i)
#pragma unroll
    for (int n = 0; n < 2; ++n) {
      acc[i][n + 2] = __builtin_amdgcn_mfma_f32_16x16x32_bf16(af[i][0], bfr[n][0], acc[i][n + 2], 0, 0, 0);
      acc[i][n + 2] = __builtin_amdgcn_mfma_f32_16x16x32_bf16(af[i][1], bfr[n][1], acc[i][n + 2], 0, 0, 0);
    }
  __builtin_amdgcn_s_setprio(0);
  __builtin_amdgcn_s_barrier();  // last reads of this buffer done before next stage
}

__global__ __launch_bounds__(512, 2) void gemm_lora_kernel(const u16* __restrict__ Abf,
                                                           const u16* __restrict__ Bbf,
                                                           float* __restrict__ out,
                                                           const float* __restrict__ bias,
                                                           const float* __restrict__ shrunk,
                                                           const float* __restrict__ lora_b,
                                                           const int* __restrict__ idx,
                                                           const int* __restrict__ list) {
  __shared__ __align__(16) char lds[98304];

  const int tid = threadIdx.x;
  const int lane = tid & 63;
  const int wave = tid >> 6;
  const int wr = wave >> 2;   // 0..1  M half (64 rows)
  const int wc = wave & 3;    // 0..3  N quarter (64 cols)
  const int quad = lane >> 4, mn = lane & 15;

  // T1: bijective XCD swizzle (nwg=256, 32 consecutive tiles per XCD)
  const int flat = blockIdx.x + 16 * blockIdx.y;
  const int swz = (flat & 7) * 32 + (flat >> 3);
  const int tx = swz & 15;        // o tile
  const int ty = swz >> 4;        // t tile (0..15), tokens taken from sorted list
  const int t0 = ty * 128;
  const int o0 = tx * 256;

  // staging: A chunk m=c*512+tid (c=0..1) -> phys (row=m>>3, slot=m&7);
  //          B chunk m=c*512+tid (c=0..3). slot holds logical cc = slot^(row&7).
  // A rows are GATHERED: row base from sorted list (global src is per-lane).
  const int srow = tid >> 3;
  const int cc = (tid & 7) ^ (srow & 7);           // c-invariant (c*64 % 8 == 0)
  const u16* const gA0 = Abf + (long)list[t0 + srow] * H_DIM + cc * 8;
  const u16* const gA1 = Abf + (long)list[t0 + 64 + srow] * H_DIM + cc * 8;
  const u16* const gB = Bbf + (long)(o0 + srow) * H_DIM + cc * 8;
  char* const dstA = lds + tid * 16;
  char* const dstB = lds + 32768 + tid * 16;

  // ds_read: logical (row, chunk k) at byte row*128 + (k ^ (row&7))*16
  const int x0 = (quad ^ (mn & 7)) * 16;           // K-slice 0
  const int x1 = ((quad + 4) ^ (mn & 7)) * 16;     // K-slice 1
  const char* const pA = lds + (wr * 64 + mn) * 128;
  const char* const pB = lds + 32768 + (wc * 64 + mn) * 128;

  floatx4 acc[4][4] = {};

  stage_tile(gA0, gA1, gB, dstA, dstB, 0, 0);  // prologue: tile 0 -> buf0 (no wait)

#pragma unroll 1
  for (int kt2 = 0; kt2 < NT; kt2 += 2) {
    // tile kt2 from buf0, stage kt2+1 -> buf1
    ktile_body(acc, pA, pB, x0, x1, 0, 0, gA0, gA1, gB, dstA, dstB, true, 1, (kt2 + 1) * BK);
    // tile kt2+1 from buf1, stage kt2+2 -> buf0
    ktile_body(acc, pA, pB, x0, x1, 16384, 32768, gA0, gA1, gB, dstA, dstB,
               kt2 + 2 < NT, 0, (kt2 + 2) * BK);
  }

  // ---- fused LoRA: acc += S(shrunk, rows) x B_l(lora_b), looped over the wave's
  // l-range (sorted tokens => contiguous, typically 1-2 values). K=r<16; quads
  // 2-3 carry k=16..31 and supply zeros. Per-row predicate masks mixed groups;
  // inactive tokens (idx=-1) never match and their shrunk rows are zero anyway.
  const int rowbase = t0 + wr * 64;
  int l0 = idx[list[rowbase]];
  int l1 = idx[list[rowbase + 63]];
  if (l0 >= 0) {
    if (l1 < 0) l1 = L_DIM - 1;  // wave spans active->inactive boundary
    const bf16x8 zf = {};
    int myl[4];
    bf16x8 sf[4];
#pragma unroll
    for (int i = 0; i < 4; ++i) {
      int tok = list[rowbase + i * 16 + mn];
      myl[i] = idx[tok];
      if (quad < 2) {
        const float4* sp = (const float4*)(shrunk + tok * R_DIM);
        sf[i] = cvt8(sp[quad * 2], sp[quad * 2 + 1]);
      } else sf[i] = zf;
    }
#pragma unroll 1
    for (int l = l0; l <= l1; ++l) {
      bf16x8 bfl[4];
#pragma unroll
      for (int n = 0; n < 4; ++n) {
        if (quad < 2) {
          const float4* bp = (const float4*)(lora_b +
              ((long)l * O_DIM + o0 + wc * 64 + n * 16 + mn) * R_DIM);
          bfl[n] = cvt8(bp[quad * 2], bp[quad * 2 + 1]);
        } else bfl[n] = zf;
      }
#pragma unroll
      for (int i = 0; i < 4; ++i) {
        bf16x8 s = (myl[i] == l) ? sf[i] : zf;
#pragma unroll
        for (int n = 0; n < 4; ++n)
          acc[i][n] = __builtin_amdgcn_mfma_f32_16x16x32_bf16(s, bfl[n], acc[i][n], 0, 0, 0);
      }
    }
  }

  // C/D layout: row = quad*4 + reg (A-tile i), col = mn (B-tile n).
  // Rows scattered via sorted list; bias fused. Each (t,o) written exactly once.
  float bv[4];
#pragma unroll
  for (int n = 0; n < 4; ++n) bv[n] = bias[o0 + wc * 64 + n * 16 + mn];
#pragma unroll
  for (int i = 0; i < 4; ++i) {
#pragma unroll
    for (int r = 0; r < 4; ++r) {
      const int trow = list[rowbase + i * 16 + quad * 4 + r];
      float* orow = out + (long)trow * O_DIM + o0 + wc * 64 + mn;
#pragma unroll
      for (int n = 0; n < 4; ++n) orow[n * 16] = acc[i][n][r] + bv[n];
    }
  }
}

extern "C" void kernel_launch(void* const* d_in, const int* in_sizes, int n_in,
                              void* d_out, int out_size, void* d_ws, size_t ws_size,
                              hipStream_t stream) {
  (void)in_sizes; (void)n_in; (void)out_size; (void)ws_size;
  const float* x      = (const float*)d_in[0];
  const float* w      = (const float*)d_in[1];
  const float* bias   = (const float*)d_in[2];
  const float* lora_a = (const float*)d_in[3];
  const float* lora_b = (const float*)d_in[4];
  const int*   idx    = (const int*)d_in[5];
  float* out = (float*)d_out;

  char* ws = (char*)d_ws;
  const size_t OFF_XB = 0;                               // 16 MiB  x bf16
  const size_t OFF_WB = (size_t)16 << 20;                // 32 MiB  w bf16
  const size_t OFF_SHRUNK = (size_t)48 << 20;            // 128 KiB
  const size_t OFF_LIST = OFF_SHRUNK + 131072;           // 8 KiB
  const size_t OFF_OFFS = OFF_LIST + 8192;               // 136 B
  const size_t OFF_AB = (size_t)49 << 20;                // 4 MiB lora_a bf16

  u16* xb = (u16*)(ws + OFF_XB);
  u16* wb = (u16*)(ws + OFF_WB);
  u16* ab = (u16*)(ws + OFF_AB);
  float* shrunk = (float*)(ws + OFF_SHRUNK);
  int* list = (int*)(ws + OFF_LIST);
  int* offs = (int*)(ws + OFF_OFFS);

  pre_kernel<<<NCVT_BLK + 1 + NZ4, 256, 0, stream>>>(
      (const float4*)x, (const float4*)w, (const float4*)lora_a,
      (ushort4*)xb, (ushort4*)wb, (ushort4*)ab, idx, offs, list, shrunk);

  lora_shrink_mfma<<<dim3(L_DIM, 4), 256, 0, stream>>>(xb, ab, offs, list, shrunk);

  dim3 grid(O_DIM / 256, T_DIM / 128);
  gemm_lora_kernel<<<grid, 512, 0, stream>>>(xb, wb, out, bias, shrunk, lora_b, idx, list);
}